// Round 2
// baseline (9.714 us; speedup 1.0000x reference)
//
#include <hip/hip_runtime.h>
#include <math.h>

#define N_DENSE   13
#define N_SPARSE  26
#define EMBED_DIM 16
#define VOCAB     100000
#define NB        2048
#define NCOL      (N_DENSE + N_SPARSE)   // 39

// 16 threads per sample: t = tid&15; dim4 = t&3 (owns embed dims 4*dim4..+3,
// one float4 of the 64B row), g = t>>2 (feature group: sizes 7,7,6,6).
// Each thread float4-gathers its group's rows, accumulates sum/sumsq per dim.
// Cross-group combine via shfl_xor(4,16) + shfl_xor(8,16); pooled = 0.5*(s^2-ss);
// dot with wout; reduce across the 4 dim4 lanes; sigmoid; store.
// (softmax over a size-1 axis == 1, so w1/b1/w2/b2 are mathematically dead.)
__global__ __launch_bounds__(256) void afm_kernel(
    const int*   __restrict__ inputs,   // (NB, 39) int32
    const float* __restrict__ tables,   // (26, VOCAB, 16) f32
    const float* __restrict__ wout,     // (16,)
    const float* __restrict__ bout,     // (1,)
    float*       __restrict__ out)      // (NB,) f32
{
    int tid  = blockIdx.x * blockDim.x + threadIdx.x;
    int b    = tid >> 4;
    int t    = tid & 15;
    int dim4 = t & 3;
    int g    = t >> 2;
    if (b >= NB) return;

    const int* idx = inputs + b * NCOL + N_DENSE;
    int start = (g < 2) ? 7 * g : 14 + 6 * (g - 2);
    int cnt   = (g < 2) ? 7 : 6;

    float s0 = 0.f, s1 = 0.f, s2 = 0.f, s3 = 0.f;
    float q0 = 0.f, q1 = 0.f, q2 = 0.f, q3 = 0.f;

    #pragma unroll
    for (int k = 0; k < 7; ++k) {
        if (k < cnt) {
            int f  = start + k;
            int ix = idx[f];
            const float4 v = *reinterpret_cast<const float4*>(
                tables + ((size_t)f * VOCAB + (size_t)ix) * EMBED_DIM + dim4 * 4);
            s0 += v.x; s1 += v.y; s2 += v.z; s3 += v.w;
            q0 += v.x * v.x; q1 += v.y * v.y; q2 += v.z * v.z; q3 += v.w * v.w;
        }
    }

    // combine the 4 feature groups (lanes differing in bits 2,3 of t)
    #pragma unroll
    for (int off = 4; off <= 8; off <<= 1) {
        s0 += __shfl_xor(s0, off, 16); s1 += __shfl_xor(s1, off, 16);
        s2 += __shfl_xor(s2, off, 16); s3 += __shfl_xor(s3, off, 16);
        q0 += __shfl_xor(q0, off, 16); q1 += __shfl_xor(q1, off, 16);
        q2 += __shfl_xor(q2, off, 16); q3 += __shfl_xor(q3, off, 16);
    }

    const float4 w = reinterpret_cast<const float4*>(wout)[dim4];
    float partial = 0.5f * ((s0 * s0 - q0) * w.x + (s1 * s1 - q1) * w.y +
                            (s2 * s2 - q2) * w.z + (s3 * s3 - q3) * w.w);

    // reduce across the 4 dim4 lanes (bits 0,1 of t)
    partial += __shfl_xor(partial, 1, 16);
    partial += __shfl_xor(partial, 2, 16);

    if (t == 0) {
        float sc = partial + bout[0];
        out[b] = 1.0f / (1.0f + expf(-sc));
    }
}

extern "C" void kernel_launch(void* const* d_in, const int* in_sizes, int n_in,
                              void* d_out, int out_size, void* d_ws, size_t ws_size,
                              hipStream_t stream) {
    const int*   inputs = (const int*)  d_in[0];
    const float* tables = (const float*)d_in[1];
    const float* wout   = (const float*)d_in[6];
    const float* bout   = (const float*)d_in[7];
    float* out = (float*)d_out;

    const int threads_per_sample = 16;
    const int block = 256;
    const int total = NB * threads_per_sample;      // 32768
    const int grid  = (total + block - 1) / block;  // 128

    afm_kernel<<<grid, block, 0, stream>>>(inputs, tables, wout, bout, out);
}